// Round 5
// baseline (111.973 us; speedup 1.0000x reference)
//
#include <hip/hip_runtime.h>

// ForwardDistance: out[b,n,m] = sum_a agg[a] * tanh(datalin[b,n,a] + critlin[b,m,a])
// tanh(x+y) = 1 - 2/(1 + e^{2x} e^{2y})
// R16: tanh LDS-throughput attack. Budget (R12-R15): ~87us fixed harness reset
// (2x256MiB poison fills, unconditional) + ~18us kernels; tanh (~12us) is
// LDS-issue-bound (128 ds_read_b128/thread x 12cyc x 16 waves/CU ~ 10.2us).
// Fix: per-thread output 4x4 -> 8x8 (LDS reads ~ n+m, outputs ~ n*m -> 4x fewer
// LDS bytes/output) + bf16 E-planes in LDS (half footprint; unpack = 1 shl/value).
// 64x64 tile, 256 thr (one WAVE per a-quarter -> wave-uniform merge), 73.7KB LDS.
// Staged ds_write chunk-order rotated per 8-row group (breaks the 144B-stride
// 8-way bank conflict); compute reads broadcast+sequential (conflict-free).
// New tanh model: VALU ~6.5us, LDS ~2.6us, staging ~1us -> ~8us (was ~12).
// proj is R15-verbatim.

#define A_DIM 256
#define K_DIM 512
#define NROWS 2048   // rows per source (B*N == B*M)

typedef unsigned short ushort;
typedef __attribute__((ext_vector_type(4))) unsigned short us4;
typedef __attribute__((ext_vector_type(8))) unsigned short us8;
typedef __attribute__((ext_vector_type(8))) short short8;   // bf16x8 MFMA frag
typedef __attribute__((ext_vector_type(4))) float f32x4;    // MFMA acc / NT stores
typedef __attribute__((ext_vector_type(2))) float f32x2;    // packed fp32

// 2 MB static intermediate: Ed bf16 [256][2048] | Ec bf16 [256][2048]
__device__ ushort g_eplanes[2 * (size_t)A_DIM * NROWS];

__device__ inline ushort f2bf(float x) {    // round-to-nearest-even bf16
    union { float f; unsigned u; } v; v.f = x;
    unsigned r = v.u + 0x7FFFu + ((v.u >> 16) & 1u);
    return (ushort)(r >> 16);
}
__device__ inline float bf2f(ushort h) {
    union { unsigned u; float f; } v; v.u = ((unsigned)h) << 16; return v.f;
}
__device__ inline unsigned pack2bf(float lo, float hi) {
    return (unsigned)f2bf(lo) | ((unsigned)f2bf(hi) << 16);
}
__device__ inline f32x2 fma2(f32x2 a, f32x2 b, f32x2 c) {
    return __builtin_elementwise_fma(a, b, c);
}

// ---- bf16 MFMA GEMM + exp2 epilogue -> Ed/Ec bf16 planes [a][row] ----
// Inline W transpose+cast: global fp32 W[k][a] -> LDS Ws[a][k-chunk] bf16, per chunk.
__global__ __launch_bounds__(256, 4) void proj_mfma_kernel(
    const float* __restrict__ data, const float* __restrict__ crit,
    const float* __restrict__ Wl, const float* __restrict__ bl,
    const float* __restrict__ Wr, const float* __restrict__ br)
{
    __shared__ ushort Ws[64][264];   // [a][k-chunk 256], pad 264 (row 528B = 33x16B)

    const int t   = threadIdx.x;
    const int bid = blockIdx.x;
    const int ct  = bid >> 7;        // a-col tile (64): consecutive bids share W slice
    const int rt  = bid & 127;       // row tile (32 rows): contiguous per XCD
    const int src = rt >> 6;
    const int lr0 = (rt & 63) * 32;
    const int c0  = ct * 64;

    const float* X    = src ? crit : data;
    const float* bias = src ? br : bl;
    const float* W    = src ? Wr : Wl;
    ushort* E = g_eplanes + (size_t)src * ((size_t)A_DIM * NROWS);

    const int lane = t & 63;
    const int wid  = t >> 6;             // 4 waves: 2 (rows) x 2 (a-cols)
    const int wm   = wid >> 1, wn = wid & 1;
    const int quad = lane >> 4, l16 = lane & 15;

    const float* xrow = X + (size_t)(lr0 + wm * 16 + l16) * K_DIM + quad * 8;
    const int aloc0 = wn * 32 + l16;

    // transpose-stage lane decode: wave w covers chunk-local k in [w*64,(w+1)*64)
    const int kq = lane >> 4;            // 0..3
    const int aq = lane & 15;            // 0..15

    f32x4 acc0 = {0.f, 0.f, 0.f, 0.f}, acc1 = {0.f, 0.f, 0.f, 0.f};

    // 2-deep rolling A prefetch (independent of LDS staging)
    float4 pa0 = *(const float4*)(xrow);
    float4 pb0 = *(const float4*)(xrow + 4);
    float4 pa1 = *(const float4*)(xrow + 32);
    float4 pb1 = *(const float4*)(xrow + 36);

    for (int kc = 0; kc < 2; kc++) {     // two 256-k chunks
        __syncthreads();                 // prior chunk's Ws reads complete
        {   // stage+transpose chunk kc: W[kc*256 + klocal][c0 + a] -> Ws[a][klocal]
#pragma unroll
            for (int p = 0; p < 4; p++) {
                const int kb = wid * 64 + p * 16;             // chunk-local k base
                f32x4 v[4];
#pragma unroll
                for (int j = 0; j < 4; j++)
                    v[j] = *(const f32x4*)(W + (size_t)(kc * 256 + kb + kq * 4 + j) * A_DIM
                                             + c0 + aq * 4);
#pragma unroll
                for (int ai = 0; ai < 4; ai++) {
                    us4 o;
#pragma unroll
                    for (int j = 0; j < 4; j++) o[j] = f2bf(v[j][ai]);
                    *(us4*)&Ws[aq * 4 + ai][kb + kq * 4] = o;
                }
            }
        }
        __syncthreads();

#pragma unroll
        for (int ls = 0; ls < 8; ls++) {
            const int s = kc * 8 + ls;
            float4 ca = pa0, cb = pb0;
            pa0 = pa1; pb0 = pb1;
            if (s < 14) {                // keep 2 A-steps in flight
                pa1 = *(const float4*)(xrow + (s + 2) * 32);
                pb1 = *(const float4*)(xrow + (s + 2) * 32 + 4);
            }
            union { short8 s8; unsigned u[4]; } af;
            af.u[0] = pack2bf(ca.x, ca.y);
            af.u[1] = pack2bf(ca.z, ca.w);
            af.u[2] = pack2bf(cb.x, cb.y);
            af.u[3] = pack2bf(cb.z, cb.w);
            short8 b0 = *(const short8*)&Ws[aloc0     ][ls * 32 + quad * 8];
            short8 b1 = *(const short8*)&Ws[aloc0 + 16][ls * 32 + quad * 8];
            acc0 = __builtin_amdgcn_mfma_f32_16x16x32_bf16(af.s8, b0, acc0, 0, 0, 0);
            acc1 = __builtin_amdgcn_mfma_f32_16x16x32_bf16(af.s8, b1, acc1, 0, 0, 0);
        }
    }

    // epilogue: C/D layout col=lane&15 (a), row=quad*4+reg. NT bf16 stores.
    const float c2 = 2.8853900817779268f;    // 2*log2(e)
    const int a_col0 = c0 + wn * 32 + l16;
    const int a_col1 = a_col0 + 16;
    const int row0   = lr0 + wm * 16 + quad * 4;
    const float bv0 = bias[a_col0], bv1 = bias[a_col1];
    us4 e0, e1;
#pragma unroll
    for (int i = 0; i < 4; i++) {
        float v0 = (acc0[i] + bv0) * c2;
        float v1 = (acc1[i] + bv1) * c2;
        v0 = fminf(fmaxf(v0, -15.f), 15.f);   // bounds q<=1+2^30 for rcp path
        v1 = fminf(fmaxf(v1, -15.f), 15.f);
        e0[i] = f2bf(__builtin_amdgcn_exp2f(v0));
        e1[i] = f2bf(__builtin_amdgcn_exp2f(v1));
    }
    __builtin_nontemporal_store(e0, (us4*)(E + (size_t)a_col0 * NROWS + row0));
    __builtin_nontemporal_store(e1, (us4*)(E + (size_t)a_col1 * NROWS + row0));
}

// ---- tanh-reduce R16: 256 thr (1 wave per a-quarter), 64x64 tile, 8n x 8m per
//      thread, bf16 LDS planes, quad-grouped rcp + f32x2 packed math ----
__global__ __launch_bounds__(256) void tanh_reduce_kernel(
    const float* __restrict__ agg, float* __restrict__ out)
{
    __shared__ __align__(16) union {
        struct { ushort et[4][64][72]; ushort ect[4][64][72]; } p;  // 73728 B
        float xb[3 * 64 * 65];                                      // 49920 B (merge)
    } sm;
    __shared__ __align__(16) float aggs[256];

    const int t  = threadIdx.x;
    const int h  = t >> 6;               // a-quarter == wave id (a in [h*64,(h+1)*64))
    const int u  = t & 63;               // lane
    const int m0 = blockIdx.x * 64;
    const int n0 = blockIdx.y * 64;
    const int b  = blockIdx.z;

    const size_t PLANE = (size_t)A_DIM * NROWS;
    const ushort* Ed = g_eplanes;
    const ushort* Ec = g_eplanes + PLANE;
    const int row_n = b * 512 + n0;
    const int row_m = b * 512 + m0;

    const int tx = u & 7;                // m chunk (8 m's)
    const int ty = u >> 3;               // n chunk (8 n's)

    if (t < 256) aggs[t] = 2.0f * agg[t];

    {   // staging: lane u stages a-row (h*64+u) of both planes, 64 cols each.
        // chunk order rotated by (u>>3)&7: breaks 144B-stride 8-way write conflict.
        const ushort* srcN = Ed + (size_t)(h * 64 + u) * NROWS + row_n;
        const ushort* srcM = Ec + (size_t)(h * 64 + u) * NROWS + row_m;
        const int key = (u >> 3) & 7;
        us8 bn[8], bm[8];
#pragma unroll
        for (int ii = 0; ii < 8; ii++) {
            const int c = ((ii + key) & 7) * 8;
            bn[ii] = *(const us8*)(srcN + c);
            bm[ii] = *(const us8*)(srcM + c);
        }
#pragma unroll
        for (int ii = 0; ii < 8; ii++) {
            const int c = ((ii + key) & 7) * 8;
            *(us8*)&sm.p.et [h][u][c] = bn[ii];
            *(us8*)&sm.p.ect[h][u][c] = bm[ii];
        }
    }

    f32x2 acc2[8][4];                    // [n i][m j-pair]
#pragma unroll
    for (int i = 0; i < 8; i++)
#pragma unroll
        for (int jp = 0; jp < 4; jp++) acc2[i][jp] = (f32x2)0.f;
    float sagg = 0.f;

    __syncthreads();

    for (int qg = 0; qg < 16; qg++) {    // a-quads: one rcp per 4 a-terms
        const float4 ag = *(const float4*)&aggs[h * 64 + qg * 4];
        sagg += (ag.x + ag.y) + (ag.z + ag.w);
        float en[4][8];                  // [a u][n i]
        f32x2 fm[4][4];                  // [a u][m j-pair]
#pragma unroll
        for (int v = 0; v < 4; v++) {    // reads: 8 distinct 16B addrs x 8-lane bcast
            us8 e8 = *(const us8*)&sm.p.et [h][qg * 4 + v][ty * 8];
            us8 f8 = *(const us8*)&sm.p.ect[h][qg * 4 + v][tx * 8];
#pragma unroll
            for (int j = 0; j < 8; j++) en[v][j] = bf2f(e8[j]);
#pragma unroll
            for (int jp = 0; jp < 4; jp++)
                fm[v][jp] = f32x2{bf2f(f8[jp * 2]), bf2f(f8[jp * 2 + 1])};
        }
#pragma unroll
        for (int i = 0; i < 8; i++)
#pragma unroll
            for (int jp = 0; jp < 4; jp++) {
                const f32x2 one = (f32x2)1.f;
                f32x2 q0 = fma2((f32x2)en[0][i], fm[0][jp], one);
                f32x2 q1 = fma2((f32x2)en[1][i], fm[1][jp], one);
                f32x2 q2 = fma2((f32x2)en[2][i], fm[2][jp], one);
                f32x2 q3 = fma2((f32x2)en[3][i], fm[3][jp], one);
                f32x2 q01 = q0 * q1, q23 = q2 * q3;
                f32x2 n01 = fma2((f32x2)ag.x, q1, (f32x2)ag.y * q0);
                f32x2 n23 = fma2((f32x2)ag.z, q3, (f32x2)ag.w * q2);
                f32x2 N   = fma2(n01, q23, n23 * q01);
                f32x2 D   = q01 * q23;              // <= 2^121, no overflow
                f32x2 r;
                r.x = __builtin_amdgcn_rcpf(D.x);
                r.y = __builtin_amdgcn_rcpf(D.y);
                acc2[i][jp] = fma2(N, r, acc2[i][jp]);
            }
    }

    // partial_h = 0.5*sagg_h - acc_h ; 4-way merge via LDS (stride 65: conflict-free)
    const float base = 0.5f * sagg;
    __syncthreads();                     // all LDS reads of et/ect complete
    if (h != 0) {                        // wave-uniform branch
        float* w = sm.xb + ((size_t)(h - 1) * 64 + u) * 65;
#pragma unroll
        for (int i = 0; i < 8; i++)
#pragma unroll
            for (int jp = 0; jp < 4; jp++) {
                w[i * 8 + jp * 2 + 0] = base - acc2[i][jp].x;
                w[i * 8 + jp * 2 + 1] = base - acc2[i][jp].y;
            }
    }
    __syncthreads();
    if (h == 0) {
        const float* x1 = sm.xb + (size_t)u * 65;
        const float* x2 = sm.xb + ((size_t)64 + u) * 65;
        const float* x3 = sm.xb + ((size_t)128 + u) * 65;
#pragma unroll
        for (int i = 0; i < 8; i++) {
            float r[8];
#pragma unroll
            for (int jp = 0; jp < 4; jp++) {
                const int k0 = i * 8 + jp * 2;
                r[jp * 2 + 0] = ((base - acc2[i][jp].x) + x1[k0 + 0]) + (x2[k0 + 0] + x3[k0 + 0]);
                r[jp * 2 + 1] = ((base - acc2[i][jp].y) + x1[k0 + 1]) + (x2[k0 + 1] + x3[k0 + 1]);
            }
            f32x4 v0 = {r[0], r[1], r[2], r[3]}, v1 = {r[4], r[5], r[6], r[7]};
            float* orow = out + (size_t)(b * 512 + n0 + ty * 8 + i) * 512 + m0 + tx * 8;
            __builtin_nontemporal_store(v0, (f32x4*)orow);
            __builtin_nontemporal_store(v1, (f32x4*)(orow + 4));
        }
    }
}

extern "C" void kernel_launch(void* const* d_in, const int* in_sizes, int n_in,
                              void* d_out, int out_size, void* d_ws, size_t ws_size,
                              hipStream_t stream) {
    const float* data = (const float*)d_in[0];
    const float* crit = (const float*)d_in[1];
    const float* Wl   = (const float*)d_in[2];
    const float* bl   = (const float*)d_in[3];
    const float* Wr   = (const float*)d_in[4];
    const float* br   = (const float*)d_in[5];
    const float* agg  = (const float*)d_in[6];
    float* out = (float*)d_out;

    (void)d_ws; (void)ws_size;   // ws unused (R15: poison is unconditional anyway)

    // proj (inline W transpose): 4 col-tiles x 128 row-tiles = 512 blocks
    proj_mfma_kernel<<<dim3(512), 256, 0, stream>>>(data, crit, Wl, bl, Wr, br);

    // tanh: (8 m x 8 n) x 4 b = 256 blocks x 256 threads; writes out directly
    tanh_reduce_kernel<<<dim3(8, 8, 4), 256, 0, stream>>>(agg, out);
}

// Round 7
// 107.528 us; speedup vs baseline: 1.0413x; 1.0413x over previous
//
#include <hip/hip_runtime.h>

// ForwardDistance: out[b,n,m] = sum_a agg[a] * tanh(datalin[b,n,a] + critlin[b,m,a])
// tanh(x+y) = 1 - 2/(1 + e^{2x} e^{2y})
// R17b: resubmission of R17 (previous bench failed on infra: "container failed
// twice" — no kernel signal). Theory unchanged:
// R16 regressed (+6us): 256thr/256blk = 1 wave/SIMD, latency-exposed. Revert to
// R12 tanh shape (1024 thr, 4x4/thread, 4 waves/SIMD) with ONE change: et (n-side)
// operand read per-qg from the L2-resident global E-plane (one-qg-ahead register
// prefetch) instead of LDS. Halves LDS instrs (8->4 reads/qg/thread, staging halved);
// moves that traffic to the idle VMEM pipe (134MB L2 ~ 4us BW, hidden under VALU).
// tanh bound: LDS 10.2us -> VALU ~7.3us. proj is R15-verbatim.

#define A_DIM 256
#define K_DIM 512
#define NROWS 2048   // rows per source (B*N == B*M)

typedef unsigned short ushort;
typedef __attribute__((ext_vector_type(4))) unsigned short us4;
typedef __attribute__((ext_vector_type(8))) unsigned short us8;
typedef __attribute__((ext_vector_type(8))) short short8;   // bf16x8 MFMA frag
typedef __attribute__((ext_vector_type(4))) float f32x4;    // MFMA acc / NT stores
typedef __attribute__((ext_vector_type(2))) float f32x2;    // packed fp32

// 2 MB static intermediate: Ed bf16 [256][2048] | Ec bf16 [256][2048]
__device__ ushort g_eplanes[2 * (size_t)A_DIM * NROWS];

__device__ inline ushort f2bf(float x) {    // round-to-nearest-even bf16
    union { float f; unsigned u; } v; v.f = x;
    unsigned r = v.u + 0x7FFFu + ((v.u >> 16) & 1u);
    return (ushort)(r >> 16);
}
__device__ inline float bf2f(ushort h) {
    union { unsigned u; float f; } v; v.u = ((unsigned)h) << 16; return v.f;
}
__device__ inline unsigned pack2bf(float lo, float hi) {
    return (unsigned)f2bf(lo) | ((unsigned)f2bf(hi) << 16);
}
__device__ inline f32x2 fma2(f32x2 a, f32x2 b, f32x2 c) {
    return __builtin_elementwise_fma(a, b, c);
}

// ---- bf16 MFMA GEMM + exp2 epilogue -> Ed/Ec bf16 planes [a][row] ----
// Inline W transpose+cast: global fp32 W[k][a] -> LDS Ws[a][k-chunk] bf16, per chunk.
__global__ __launch_bounds__(256, 4) void proj_mfma_kernel(
    const float* __restrict__ data, const float* __restrict__ crit,
    const float* __restrict__ Wl, const float* __restrict__ bl,
    const float* __restrict__ Wr, const float* __restrict__ br)
{
    __shared__ ushort Ws[64][264];   // [a][k-chunk 256], pad 264 (row 528B = 33x16B)

    const int t   = threadIdx.x;
    const int bid = blockIdx.x;
    const int ct  = bid >> 7;        // a-col tile (64): consecutive bids share W slice
    const int rt  = bid & 127;       // row tile (32 rows): contiguous per XCD
    const int src = rt >> 6;
    const int lr0 = (rt & 63) * 32;
    const int c0  = ct * 64;

    const float* X    = src ? crit : data;
    const float* bias = src ? br : bl;
    const float* W    = src ? Wr : Wl;
    ushort* E = g_eplanes + (size_t)src * ((size_t)A_DIM * NROWS);

    const int lane = t & 63;
    const int wid  = t >> 6;             // 4 waves: 2 (rows) x 2 (a-cols)
    const int wm   = wid >> 1, wn = wid & 1;
    const int quad = lane >> 4, l16 = lane & 15;

    const float* xrow = X + (size_t)(lr0 + wm * 16 + l16) * K_DIM + quad * 8;
    const int aloc0 = wn * 32 + l16;

    // transpose-stage lane decode: wave w covers chunk-local k in [w*64,(w+1)*64)
    const int kq = lane >> 4;            // 0..3
    const int aq = lane & 15;            // 0..15

    f32x4 acc0 = {0.f, 0.f, 0.f, 0.f}, acc1 = {0.f, 0.f, 0.f, 0.f};

    // 2-deep rolling A prefetch (independent of LDS staging)
    float4 pa0 = *(const float4*)(xrow);
    float4 pb0 = *(const float4*)(xrow + 4);
    float4 pa1 = *(const float4*)(xrow + 32);
    float4 pb1 = *(const float4*)(xrow + 36);

    for (int kc = 0; kc < 2; kc++) {     // two 256-k chunks
        __syncthreads();                 // prior chunk's Ws reads complete
        {   // stage+transpose chunk kc: W[kc*256 + klocal][c0 + a] -> Ws[a][klocal]
#pragma unroll
            for (int p = 0; p < 4; p++) {
                const int kb = wid * 64 + p * 16;             // chunk-local k base
                f32x4 v[4];
#pragma unroll
                for (int j = 0; j < 4; j++)
                    v[j] = *(const f32x4*)(W + (size_t)(kc * 256 + kb + kq * 4 + j) * A_DIM
                                             + c0 + aq * 4);
#pragma unroll
                for (int ai = 0; ai < 4; ai++) {
                    us4 o;
#pragma unroll
                    for (int j = 0; j < 4; j++) o[j] = f2bf(v[j][ai]);
                    *(us4*)&Ws[aq * 4 + ai][kb + kq * 4] = o;
                }
            }
        }
        __syncthreads();

#pragma unroll
        for (int ls = 0; ls < 8; ls++) {
            const int s = kc * 8 + ls;
            float4 ca = pa0, cb = pb0;
            pa0 = pa1; pb0 = pb1;
            if (s < 14) {                // keep 2 A-steps in flight
                pa1 = *(const float4*)(xrow + (s + 2) * 32);
                pb1 = *(const float4*)(xrow + (s + 2) * 32 + 4);
            }
            union { short8 s8; unsigned u[4]; } af;
            af.u[0] = pack2bf(ca.x, ca.y);
            af.u[1] = pack2bf(ca.z, ca.w);
            af.u[2] = pack2bf(cb.x, cb.y);
            af.u[3] = pack2bf(cb.z, cb.w);
            short8 b0 = *(const short8*)&Ws[aloc0     ][ls * 32 + quad * 8];
            short8 b1 = *(const short8*)&Ws[aloc0 + 16][ls * 32 + quad * 8];
            acc0 = __builtin_amdgcn_mfma_f32_16x16x32_bf16(af.s8, b0, acc0, 0, 0, 0);
            acc1 = __builtin_amdgcn_mfma_f32_16x16x32_bf16(af.s8, b1, acc1, 0, 0, 0);
        }
    }

    // epilogue: C/D layout col=lane&15 (a), row=quad*4+reg. NT bf16 stores.
    const float c2 = 2.8853900817779268f;    // 2*log2(e)
    const int a_col0 = c0 + wn * 32 + l16;
    const int a_col1 = a_col0 + 16;
    const int row0   = lr0 + wm * 16 + quad * 4;
    const float bv0 = bias[a_col0], bv1 = bias[a_col1];
    us4 e0, e1;
#pragma unroll
    for (int i = 0; i < 4; i++) {
        float v0 = (acc0[i] + bv0) * c2;
        float v1 = (acc1[i] + bv1) * c2;
        v0 = fminf(fmaxf(v0, -15.f), 15.f);   // bounds q<=1+2^30 for rcp path
        v1 = fminf(fmaxf(v1, -15.f), 15.f);
        e0[i] = f2bf(__builtin_amdgcn_exp2f(v0));
        e1[i] = f2bf(__builtin_amdgcn_exp2f(v1));
    }
    __builtin_nontemporal_store(e0, (us4*)(E + (size_t)a_col0 * NROWS + row0));
    __builtin_nontemporal_store(e1, (us4*)(E + (size_t)a_col1 * NROWS + row0));
}

// ---- tanh-reduce R17: 1024 thr, 64x64 tile, 4 a-quarters, 4x4/thread;
//      ect staged in LDS, et read from L2-resident global w/ 1-qg-ahead prefetch ----
__global__ __launch_bounds__(1024) void tanh_reduce_kernel(
    const float* __restrict__ agg, float* __restrict__ out)
{
    __shared__ __align__(16) float ect[4][64][68];   // [quarter][a][m]  69632 B
    __shared__ __align__(16) float aggs[256];

    const int t  = threadIdx.x;
    const int h  = t >> 8;               // a-quarter (a in [h*64, h*64+64))
    const int u  = t & 255;              // thread id within quarter
    const int m0 = blockIdx.x * 64;
    const int n0 = blockIdx.y * 64;
    const int b  = blockIdx.z;

    const size_t PLANE = (size_t)A_DIM * NROWS;
    const ushort* Ed = g_eplanes;
    const ushort* Ec = g_eplanes + PLANE;
    const int row_n = b * 512 + n0;
    const int row_m = b * 512 + m0;

    const int tx = u & 15;               // m group (4 m's)
    const int ty = u >> 4;               // n group (4 n's)

    if (t < 256) aggs[t] = 2.0f * agg[t];

    f32x2 acc2[4][2];                    // [n i][m j-pair]
#pragma unroll
    for (int i = 0; i < 4; i++) { acc2[i][0] = (f32x2)0.f; acc2[i][1] = (f32x2)0.f; }
    float sagg = 0.f;

    const int aL = u >> 2;               // staging row 0..63
    const int qd = u & 3;                // staging quarter (16 cols each)

    float (*ecth)[68] = ect[h];

    {   // stage ect ONLY (et comes from global per-qg)
        const size_t base = (size_t)(h * 64 + aL) * NROWS;
        us4 pm[4];
#pragma unroll
        for (int r = 0; r < 4; r++)
            pm[r] = *(const us4*)(Ec + base + row_m + qd * 16 + r * 4);
#pragma unroll
        for (int r = 0; r < 4; r++) {
            float4 cv;
            cv.x = bf2f(pm[r][0]); cv.y = bf2f(pm[r][1]);
            cv.z = bf2f(pm[r][2]); cv.w = bf2f(pm[r][3]);
            *(float4*)&ecth[aL][qd * 16 + r * 4] = cv;
        }
    }

    // et global base for this thread's 4 n's; prefetch qg=0 (L2-resident, 8B loads)
    const ushort* EdN = Ed + (size_t)(h * 64) * NROWS + row_n + ty * 4;
    us4 pe[4];
#pragma unroll
    for (int v = 0; v < 4; v++)
        pe[v] = *(const us4*)(EdN + (size_t)v * NROWS);

    __syncthreads();

    for (int qg = 0; qg < 16; qg++) {    // a-quads: one rcp per 4 a-terms
        const float4 ag = *(const float4*)&aggs[h * 64 + qg * 4];
        sagg += (ag.x + ag.y) + (ag.z + ag.w);
        us4 ce[4];
#pragma unroll
        for (int v = 0; v < 4; v++) ce[v] = pe[v];
        if (qg < 15) {                   // prefetch next qg's et under compute
#pragma unroll
            for (int v = 0; v < 4; v++)
                pe[v] = *(const us4*)(EdN + (size_t)((qg + 1) * 4 + v) * NROWS);
        }
        float  en[4][4];                 // [a u][n i]
        f32x2  fm[4][2];                 // [a u][m j-pair]
#pragma unroll
        for (int v = 0; v < 4; v++) {
            en[v][0] = bf2f(ce[v][0]); en[v][1] = bf2f(ce[v][1]);
            en[v][2] = bf2f(ce[v][2]); en[v][3] = bf2f(ce[v][3]);
            float4 f4 = *(const float4*)&ecth[qg * 4 + v][tx * 4];
            fm[v][0] = f32x2{f4.x, f4.y};
            fm[v][1] = f32x2{f4.z, f4.w};
        }
#pragma unroll
        for (int i = 0; i < 4; i++)
#pragma unroll
            for (int jp = 0; jp < 2; jp++) {
                const f32x2 one = (f32x2)1.f;
                f32x2 q0 = fma2((f32x2)en[0][i], fm[0][jp], one);
                f32x2 q1 = fma2((f32x2)en[1][i], fm[1][jp], one);
                f32x2 q2 = fma2((f32x2)en[2][i], fm[2][jp], one);
                f32x2 q3 = fma2((f32x2)en[3][i], fm[3][jp], one);
                f32x2 q01 = q0 * q1, q23 = q2 * q3;
                f32x2 n01 = fma2((f32x2)ag.x, q1, (f32x2)ag.y * q0);
                f32x2 n23 = fma2((f32x2)ag.z, q3, (f32x2)ag.w * q2);
                f32x2 N   = fma2(n01, q23, n23 * q01);
                f32x2 D   = q01 * q23;              // <= 2^121, no overflow
                f32x2 r;
                r.x = __builtin_amdgcn_rcpf(D.x);
                r.y = __builtin_amdgcn_rcpf(D.y);
                acc2[i][jp] = fma2(N, r, acc2[i][jp]);
            }
    }

    // partial_h = 0.5*sagg_h - acc_h ; 4-way merge via LDS (stride 17: conflict-free)
    const float base = 0.5f * sagg;
    float* xb = (float*)ect;             // reuse (3*256*17 floats = 52 KB < 69.6 KB)
    __syncthreads();                     // all LDS reads of ect complete
    if (h != 0) {
        float* w = xb + ((size_t)(h - 1) * 256 + u) * 17;
#pragma unroll
        for (int i = 0; i < 4; i++)
#pragma unroll
            for (int jp = 0; jp < 2; jp++) {
                w[i * 4 + jp * 2 + 0] = base - acc2[i][jp].x;
                w[i * 4 + jp * 2 + 1] = base - acc2[i][jp].y;
            }
    }
    __syncthreads();
    if (h == 0) {
        const float* x1 = xb + (size_t)u * 17;
        const float* x2 = xb + ((size_t)256 + u) * 17;
        const float* x3 = xb + ((size_t)512 + u) * 17;
#pragma unroll
        for (int i = 0; i < 4; i++) {
            f32x4 v;
            v.x = ((base - acc2[i][0].x) + x1[i * 4 + 0]) + (x2[i * 4 + 0] + x3[i * 4 + 0]);
            v.y = ((base - acc2[i][0].y) + x1[i * 4 + 1]) + (x2[i * 4 + 1] + x3[i * 4 + 1]);
            v.z = ((base - acc2[i][1].x) + x1[i * 4 + 2]) + (x2[i * 4 + 2] + x3[i * 4 + 2]);
            v.w = ((base - acc2[i][1].y) + x1[i * 4 + 3]) + (x2[i * 4 + 3] + x3[i * 4 + 3]);
            __builtin_nontemporal_store(v,
                (f32x4*)(out + ((size_t)(b * 512 + n0 + ty * 4 + i) * 512) + m0 + tx * 4));
        }
    }
}

extern "C" void kernel_launch(void* const* d_in, const int* in_sizes, int n_in,
                              void* d_out, int out_size, void* d_ws, size_t ws_size,
                              hipStream_t stream) {
    const float* data = (const float*)d_in[0];
    const float* crit = (const float*)d_in[1];
    const float* Wl   = (const float*)d_in[2];
    const float* bl   = (const float*)d_in[3];
    const float* Wr   = (const float*)d_in[4];
    const float* br   = (const float*)d_in[5];
    const float* agg  = (const float*)d_in[6];
    float* out = (float*)d_out;

    (void)d_ws; (void)ws_size;   // ws unused (R15: poison is unconditional anyway)

    // proj (inline W transpose): 4 col-tiles x 128 row-tiles = 512 blocks
    proj_mfma_kernel<<<dim3(512), 256, 0, stream>>>(data, crit, Wl, bl, Wr, br);

    // tanh: (8 m x 8 n) x 4 b = 256 blocks x 1024 threads; writes out directly
    tanh_reduce_kernel<<<dim3(8, 8, 4), 1024, 0, stream>>>(agg, out);
}

// Round 8
// 105.539 us; speedup vs baseline: 1.0610x; 1.0188x over previous
//
#include <hip/hip_runtime.h>

// ForwardDistance: out[b,n,m] = sum_a agg[a] * tanh(datalin[b,n,a] + critlin[b,m,a])
// tanh(x+y) = 1 - 2/(1 + e^{2x} e^{2y})
// R18: revert to best-measured configuration (R14/R15 = 105.8/105.9 us).
// Ledger: R12 restructure 107.2 | R13 coop-fusion 181 (grid.sync ~30us each) |
// R14 2-dispatch 105.8 (BEST) | R15 ws-bypass null (poison unconditional) |
// R16 8x8/thread 112.0 (1 wave/SIMD latency-exposed) | R17 et-from-global 107.5.
// Conclusion: measured region = ~88us unconditional harness reset (2x256MiB fills
// at 80-82% HBM peak, themselves at the memory roofline) + ~18us near-floor kernels
// (proj ~10us MFMA/L2-bound, tanh ~12us mixed VALU/LDS with 4 waves/SIMD).
// Three tanh attacks (R16 blocking, R17 pipe-rebalance) all failed to beat R12's
// tanh -> practical floor. This is the final kernel: R15 source verbatim.

#define A_DIM 256
#define K_DIM 512
#define NROWS 2048   // rows per source (B*N == B*M)

typedef unsigned short ushort;
typedef __attribute__((ext_vector_type(4))) unsigned short us4;
typedef __attribute__((ext_vector_type(8))) unsigned short us8;
typedef __attribute__((ext_vector_type(8))) short short8;   // bf16x8 MFMA frag
typedef __attribute__((ext_vector_type(4))) float f32x4;    // MFMA acc / NT stores
typedef __attribute__((ext_vector_type(2))) float f32x2;    // packed fp32

// 2 MB static intermediate: Ed bf16 [256][2048] | Ec bf16 [256][2048]
__device__ ushort g_eplanes[2 * (size_t)A_DIM * NROWS];

__device__ inline ushort f2bf(float x) {    // round-to-nearest-even bf16
    union { float f; unsigned u; } v; v.f = x;
    unsigned r = v.u + 0x7FFFu + ((v.u >> 16) & 1u);
    return (ushort)(r >> 16);
}
__device__ inline float bf2f(ushort h) {
    union { unsigned u; float f; } v; v.u = ((unsigned)h) << 16; return v.f;
}
__device__ inline unsigned pack2bf(float lo, float hi) {
    return (unsigned)f2bf(lo) | ((unsigned)f2bf(hi) << 16);
}
__device__ inline f32x2 fma2(f32x2 a, f32x2 b, f32x2 c) {
    return __builtin_elementwise_fma(a, b, c);
}

// ---- bf16 MFMA GEMM + exp2 epilogue -> Ed/Ec bf16 planes [a][row] ----
// Inline W transpose+cast: global fp32 W[k][a] -> LDS Ws[a][k-chunk] bf16, per chunk.
__global__ __launch_bounds__(256, 4) void proj_mfma_kernel(
    const float* __restrict__ data, const float* __restrict__ crit,
    const float* __restrict__ Wl, const float* __restrict__ bl,
    const float* __restrict__ Wr, const float* __restrict__ br)
{
    __shared__ ushort Ws[64][264];   // [a][k-chunk 256], pad 264 (row 528B = 33x16B)

    const int t   = threadIdx.x;
    const int bid = blockIdx.x;
    const int ct  = bid >> 7;        // a-col tile (64): consecutive bids share W slice
    const int rt  = bid & 127;       // row tile (32 rows): contiguous per XCD
    const int src = rt >> 6;
    const int lr0 = (rt & 63) * 32;
    const int c0  = ct * 64;

    const float* X    = src ? crit : data;
    const float* bias = src ? br : bl;
    const float* W    = src ? Wr : Wl;
    ushort* E = g_eplanes + (size_t)src * ((size_t)A_DIM * NROWS);

    const int lane = t & 63;
    const int wid  = t >> 6;             // 4 waves: 2 (rows) x 2 (a-cols)
    const int wm   = wid >> 1, wn = wid & 1;
    const int quad = lane >> 4, l16 = lane & 15;

    const float* xrow = X + (size_t)(lr0 + wm * 16 + l16) * K_DIM + quad * 8;
    const int aloc0 = wn * 32 + l16;

    // transpose-stage lane decode: wave w covers chunk-local k in [w*64,(w+1)*64)
    const int kq = lane >> 4;            // 0..3
    const int aq = lane & 15;            // 0..15

    f32x4 acc0 = {0.f, 0.f, 0.f, 0.f}, acc1 = {0.f, 0.f, 0.f, 0.f};

    // 2-deep rolling A prefetch (independent of LDS staging)
    float4 pa0 = *(const float4*)(xrow);
    float4 pb0 = *(const float4*)(xrow + 4);
    float4 pa1 = *(const float4*)(xrow + 32);
    float4 pb1 = *(const float4*)(xrow + 36);

    for (int kc = 0; kc < 2; kc++) {     // two 256-k chunks
        __syncthreads();                 // prior chunk's Ws reads complete
        {   // stage+transpose chunk kc: W[kc*256 + klocal][c0 + a] -> Ws[a][klocal]
#pragma unroll
            for (int p = 0; p < 4; p++) {
                const int kb = wid * 64 + p * 16;             // chunk-local k base
                f32x4 v[4];
#pragma unroll
                for (int j = 0; j < 4; j++)
                    v[j] = *(const f32x4*)(W + (size_t)(kc * 256 + kb + kq * 4 + j) * A_DIM
                                             + c0 + aq * 4);
#pragma unroll
                for (int ai = 0; ai < 4; ai++) {
                    us4 o;
#pragma unroll
                    for (int j = 0; j < 4; j++) o[j] = f2bf(v[j][ai]);
                    *(us4*)&Ws[aq * 4 + ai][kb + kq * 4] = o;
                }
            }
        }
        __syncthreads();

#pragma unroll
        for (int ls = 0; ls < 8; ls++) {
            const int s = kc * 8 + ls;
            float4 ca = pa0, cb = pb0;
            pa0 = pa1; pb0 = pb1;
            if (s < 14) {                // keep 2 A-steps in flight
                pa1 = *(const float4*)(xrow + (s + 2) * 32);
                pb1 = *(const float4*)(xrow + (s + 2) * 32 + 4);
            }
            union { short8 s8; unsigned u[4]; } af;
            af.u[0] = pack2bf(ca.x, ca.y);
            af.u[1] = pack2bf(ca.z, ca.w);
            af.u[2] = pack2bf(cb.x, cb.y);
            af.u[3] = pack2bf(cb.z, cb.w);
            short8 b0 = *(const short8*)&Ws[aloc0     ][ls * 32 + quad * 8];
            short8 b1 = *(const short8*)&Ws[aloc0 + 16][ls * 32 + quad * 8];
            acc0 = __builtin_amdgcn_mfma_f32_16x16x32_bf16(af.s8, b0, acc0, 0, 0, 0);
            acc1 = __builtin_amdgcn_mfma_f32_16x16x32_bf16(af.s8, b1, acc1, 0, 0, 0);
        }
    }

    // epilogue: C/D layout col=lane&15 (a), row=quad*4+reg. NT bf16 stores.
    const float c2 = 2.8853900817779268f;    // 2*log2(e)
    const int a_col0 = c0 + wn * 32 + l16;
    const int a_col1 = a_col0 + 16;
    const int row0   = lr0 + wm * 16 + quad * 4;
    const float bv0 = bias[a_col0], bv1 = bias[a_col1];
    us4 e0, e1;
#pragma unroll
    for (int i = 0; i < 4; i++) {
        float v0 = (acc0[i] + bv0) * c2;
        float v1 = (acc1[i] + bv1) * c2;
        v0 = fminf(fmaxf(v0, -15.f), 15.f);   // bounds q<=1+2^30 for rcp path
        v1 = fminf(fmaxf(v1, -15.f), 15.f);
        e0[i] = f2bf(__builtin_amdgcn_exp2f(v0));
        e1[i] = f2bf(__builtin_amdgcn_exp2f(v1));
    }
    __builtin_nontemporal_store(e0, (us4*)(E + (size_t)a_col0 * NROWS + row0));
    __builtin_nontemporal_store(e1, (us4*)(E + (size_t)a_col1 * NROWS + row0));
}

// ---- tanh-reduce: 1024 thr, 64x64 tile, a-QUARTERS across wave groups,
//      single-shot staging, quad-grouped rcp + f32x2 packed math (R12-verbatim) ----
__global__ __launch_bounds__(1024) void tanh_reduce_kernel(
    const float* __restrict__ agg, float* __restrict__ out)
{
    __shared__ __align__(16) float et [4][64][68];   // [quarter][a][n]  69632 B
    __shared__ __align__(16) float ect[4][64][68];   // [quarter][a][m]  69632 B
    __shared__ __align__(16) float aggs[256];

    const int t  = threadIdx.x;
    const int h  = t >> 8;               // a-quarter (a in [h*64, h*64+64))
    const int u  = t & 255;              // thread id within quarter
    const int m0 = blockIdx.x * 64;
    const int n0 = blockIdx.y * 64;
    const int b  = blockIdx.z;

    const size_t PLANE = (size_t)A_DIM * NROWS;
    const ushort* Ed = g_eplanes;
    const ushort* Ec = g_eplanes + PLANE;
    const int row_n = b * 512 + n0;
    const int row_m = b * 512 + m0;

    const int tx = u & 15;               // m group (4 m's)
    const int ty = u >> 4;               // n group (4 n's)

    if (t < 256) aggs[t] = 2.0f * agg[t];

    f32x2 acc2[4][2];                    // [n i][m j-pair]
#pragma unroll
    for (int i = 0; i < 4; i++) { acc2[i][0] = (f32x2)0.f; acc2[i][1] = (f32x2)0.f; }
    float sagg = 0.f;

    const int aL = u >> 2;               // staging row 0..63
    const int qd = u & 3;                // staging quarter (16 cols each)

    float (*eth)[68]  = et[h];
    float (*ecth)[68] = ect[h];

    {   // single-shot staging: quarter h stages its 64 a-rows of both planes
        const size_t base = (size_t)(h * 64 + aL) * NROWS;
        us4 pn[4], pm[4];
#pragma unroll
        for (int r = 0; r < 4; r++) {
            pn[r] = *(const us4*)(Ed + base + row_n + qd * 16 + r * 4);
            pm[r] = *(const us4*)(Ec + base + row_m + qd * 16 + r * 4);
        }
#pragma unroll
        for (int r = 0; r < 4; r++) {
            float4 ev, cv;
            ev.x = bf2f(pn[r][0]); ev.y = bf2f(pn[r][1]);
            ev.z = bf2f(pn[r][2]); ev.w = bf2f(pn[r][3]);
            cv.x = bf2f(pm[r][0]); cv.y = bf2f(pm[r][1]);
            cv.z = bf2f(pm[r][2]); cv.w = bf2f(pm[r][3]);
            *(float4*)&eth [aL][qd * 16 + r * 4] = ev;
            *(float4*)&ecth[aL][qd * 16 + r * 4] = cv;
        }
    }
    __syncthreads();

    for (int qg = 0; qg < 16; qg++) {    // a-quads: one rcp per 4 a-terms
        const float4 ag = *(const float4*)&aggs[h * 64 + qg * 4];
        sagg += (ag.x + ag.y) + (ag.z + ag.w);
        float  en[4][4];                 // [a u][n i]
        f32x2  fm[4][2];                 // [a u][m j-pair]
#pragma unroll
        for (int v = 0; v < 4; v++) {
            float4 e4 = *(const float4*)&eth [qg * 4 + v][ty * 4];
            float4 f4 = *(const float4*)&ecth[qg * 4 + v][tx * 4];
            en[v][0] = e4.x; en[v][1] = e4.y; en[v][2] = e4.z; en[v][3] = e4.w;
            fm[v][0] = f32x2{f4.x, f4.y};
            fm[v][1] = f32x2{f4.z, f4.w};
        }
#pragma unroll
        for (int i = 0; i < 4; i++)
#pragma unroll
            for (int jp = 0; jp < 2; jp++) {
                const f32x2 one = (f32x2)1.f;
                f32x2 q0 = fma2((f32x2)en[0][i], fm[0][jp], one);
                f32x2 q1 = fma2((f32x2)en[1][i], fm[1][jp], one);
                f32x2 q2 = fma2((f32x2)en[2][i], fm[2][jp], one);
                f32x2 q3 = fma2((f32x2)en[3][i], fm[3][jp], one);
                f32x2 q01 = q0 * q1, q23 = q2 * q3;
                f32x2 n01 = fma2((f32x2)ag.x, q1, (f32x2)ag.y * q0);
                f32x2 n23 = fma2((f32x2)ag.z, q3, (f32x2)ag.w * q2);
                f32x2 N   = fma2(n01, q23, n23 * q01);
                f32x2 D   = q01 * q23;              // <= 2^121, no overflow
                f32x2 r;
                r.x = __builtin_amdgcn_rcpf(D.x);
                r.y = __builtin_amdgcn_rcpf(D.y);
                acc2[i][jp] = fma2(N, r, acc2[i][jp]);
            }
    }

    // partial_h = 0.5*sagg_h - acc_h ; 4-way merge via LDS (stride 17: conflict-free)
    const float base = 0.5f * sagg;
    float* xb = (float*)ect;             // reuse (3*256*17 floats = 52 KB < 69.6 KB)
    __syncthreads();                     // all LDS reads of et/ect complete
    if (h != 0) {
        float* w = xb + ((size_t)(h - 1) * 256 + u) * 17;
#pragma unroll
        for (int i = 0; i < 4; i++)
#pragma unroll
            for (int jp = 0; jp < 2; jp++) {
                w[i * 4 + jp * 2 + 0] = base - acc2[i][jp].x;
                w[i * 4 + jp * 2 + 1] = base - acc2[i][jp].y;
            }
    }
    __syncthreads();
    if (h == 0) {
        const float* x1 = xb + (size_t)u * 17;
        const float* x2 = xb + ((size_t)256 + u) * 17;
        const float* x3 = xb + ((size_t)512 + u) * 17;
#pragma unroll
        for (int i = 0; i < 4; i++) {
            f32x4 v;
            v.x = ((base - acc2[i][0].x) + x1[i * 4 + 0]) + (x2[i * 4 + 0] + x3[i * 4 + 0]);
            v.y = ((base - acc2[i][0].y) + x1[i * 4 + 1]) + (x2[i * 4 + 1] + x3[i * 4 + 1]);
            v.z = ((base - acc2[i][1].x) + x1[i * 4 + 2]) + (x2[i * 4 + 2] + x3[i * 4 + 2]);
            v.w = ((base - acc2[i][1].y) + x1[i * 4 + 3]) + (x2[i * 4 + 3] + x3[i * 4 + 3]);
            __builtin_nontemporal_store(v,
                (f32x4*)(out + ((size_t)(b * 512 + n0 + ty * 4 + i) * 512) + m0 + tx * 4));
        }
    }
}

extern "C" void kernel_launch(void* const* d_in, const int* in_sizes, int n_in,
                              void* d_out, int out_size, void* d_ws, size_t ws_size,
                              hipStream_t stream) {
    const float* data = (const float*)d_in[0];
    const float* crit = (const float*)d_in[1];
    const float* Wl   = (const float*)d_in[2];
    const float* bl   = (const float*)d_in[3];
    const float* Wr   = (const float*)d_in[4];
    const float* br   = (const float*)d_in[5];
    const float* agg  = (const float*)d_in[6];
    float* out = (float*)d_out;

    (void)d_ws; (void)ws_size;   // ws unused (R15: poison is unconditional)

    // proj (inline W transpose): 4 col-tiles x 128 row-tiles = 512 blocks
    proj_mfma_kernel<<<dim3(512), 256, 0, stream>>>(data, crit, Wl, bl, Wr, br);

    // tanh: (8 m x 8 n) x 4 b = 256 blocks x 1024 threads; writes out directly
    tanh_reduce_kernel<<<dim3(8, 8, 4), 1024, 0, stream>>>(agg, out);
}